// Round 2
// baseline (64.320 us; speedup 1.0000x reference)
//
#include <hip/hip_runtime.h>

// Problem constants (from reference)
#define B_    16
#define N_    25200
#define NC_   80
#define NM_   32
#define NDET_ 100
#define H_    160
#define W_    160
#define HW_   (H_ * W_)
#define XDIM_ (5 + NC_ + NM_)   // 117
#define COEF_OFF_ (5 + NC_)     // 85

// Output layout (flat f32):
// [0,16)          num_det (int->float)
// [16,6416)       det_boxes
// [6416,8016)     det_scores
// [8016,9616)     det_classes (int->float)
// [9616, ...)     masks (B*NDET*HW)
#define OFF_BOXES_   16
#define OFF_SCORES_  6416
#define OFF_CLASSES_ 8016
#define OFF_MASKS_   9616

typedef float f32x4 __attribute__((ext_vector_type(4)));

// One block = 1 wave (64 threads), 4 pixels/thread -> 256 px/block.
// Grid: (HW/256 = 100 tiles, B = 16 batches) = 1600 blocks.
__global__ __launch_bounds__(64) void mask_kernel(
    const float* __restrict__ x0,
    const float* __restrict__ proto,
    const int*   __restrict__ num_det,
    const float* __restrict__ det_boxes,
    const float* __restrict__ det_scores,
    const int*   __restrict__ det_classes,
    const int*   __restrict__ det_indices,
    float* __restrict__ out)
{
    __shared__ float s_coef[NDET_ * NM_];   // 12.8 KB
    __shared__ f32x4 s_box[NDET_];          // 1.6 KB, prescaled

    const int b    = blockIdx.y;
    const int tile = blockIdx.x;
    const int tid  = threadIdx.x;

    // Gather coefficient matrix for this batch into LDS (L2-hit after first block).
    for (int i = tid; i < NDET_ * NM_; i += 64) {
        int o = i >> 5;
        int m = i & 31;
        int idx = det_indices[b * NDET_ + o];
        s_coef[i] = x0[((size_t)b * N_ + idx) * XDIM_ + COEF_OFF_ + m];
    }
    for (int i = tid; i < NDET_; i += 64) {
        f32x4 bx = ((const f32x4*)det_boxes)[b * NDET_ + i];
        s_box[i] = bx * 0.25f;
    }

    // Fused head outputs: tile-0 block of each batch writes the small outputs.
    if (tile == 0) {
        if (tid == 0) out[b] = (float)num_det[b];
        for (int i = tid; i < NDET_ * 4; i += 64)
            out[OFF_BOXES_ + b * NDET_ * 4 + i] = det_boxes[b * NDET_ * 4 + i];
        for (int i = tid; i < NDET_; i += 64) {
            out[OFF_SCORES_  + b * NDET_ + i] = det_scores[b * NDET_ + i];
            out[OFF_CLASSES_ + b * NDET_ + i] = (float)det_classes[b * NDET_ + i];
        }
    }
    __syncthreads();

    const int p = tile * 256 + tid * 4;          // 4-aligned; W=160 % 4 == 0 -> same row
    const float cf  = (float)(p / W_);
    const float rf0 = (float)(p % W_);

    // This thread's 4 proto columns, 32 deep, in registers (128 VGPRs).
    const float* __restrict__ pp = proto + (size_t)b * NM_ * HW_ + p;
    f32x4 pr[NM_];
#pragma unroll
    for (int m = 0; m < NM_; ++m)
        pr[m] = __builtin_nontemporal_load((const f32x4*)(pp + (size_t)m * HW_));

    float* __restrict__ outp = out + OFF_MASKS_ + (size_t)b * NDET_ * HW_ + p;

    for (int o = 0; o < NDET_; ++o) {
        const f32x4 bx = s_box[o];
        f32x4 v = {0.f, 0.f, 0.f, 0.f};
        const bool iny = (cf >= bx.y) & (cf < bx.w);
        const bool in0 = iny & (rf0        >= bx.x) & (rf0        < bx.z);
        const bool in1 = iny & (rf0 + 1.f  >= bx.x) & (rf0 + 1.f  < bx.z);
        const bool in2 = iny & (rf0 + 2.f  >= bx.x) & (rf0 + 2.f  < bx.z);
        const bool in3 = iny & (rf0 + 3.f  >= bx.x) & (rf0 + 3.f  < bx.z);
        if (in0 | in1 | in2 | in3) {
            f32x4 acc = {0.f, 0.f, 0.f, 0.f};
#pragma unroll
            for (int m = 0; m < NM_; ++m) acc += s_coef[o * NM_ + m] * pr[m];
            v[0] = in0 ? 1.f / (1.f + __expf(-acc[0])) : 0.f;
            v[1] = in1 ? 1.f / (1.f + __expf(-acc[1])) : 0.f;
            v[2] = in2 ? 1.f / (1.f + __expf(-acc[2])) : 0.f;
            v[3] = in3 ? 1.f / (1.f + __expf(-acc[3])) : 0.f;
        }
        __builtin_nontemporal_store(v, (f32x4*)(outp + (size_t)o * HW_));
    }
}

extern "C" void kernel_launch(void* const* d_in, const int* in_sizes, int n_in,
                              void* d_out, int out_size, void* d_ws, size_t ws_size,
                              hipStream_t stream)
{
    const float* x0          = (const float*)d_in[0];
    const float* proto       = (const float*)d_in[1];
    const int*   num_det     = (const int*)  d_in[2];
    const float* det_boxes   = (const float*)d_in[3];
    const float* det_scores  = (const float*)d_in[4];
    const int*   det_classes = (const int*)  d_in[5];
    const int*   det_indices = (const int*)  d_in[6];
    float* out = (float*)d_out;

    dim3 grid(HW_ / 256, B_);
    mask_kernel<<<grid, 64, 0, stream>>>(
        x0, proto, num_det, det_boxes, det_scores, det_classes, det_indices, out);
}

// Round 3
// 49.180 us; speedup vs baseline: 1.3078x; 1.3078x over previous
//
#include <hip/hip_runtime.h>

// Problem constants (from reference)
#define B_    16
#define N_    25200
#define NC_   80
#define NM_   32
#define NDET_ 100
#define H_    160
#define W_    160
#define HW_   (H_ * W_)
#define XDIM_ (5 + NC_ + NM_)   // 117
#define COEF_OFF_ (5 + NC_)     // 85

// Output layout (flat f32):
#define OFF_BOXES_   16
#define OFF_SCORES_  6416
#define OFF_CLASSES_ 8016
#define OFF_MASKS_   9616

// Workspace layout (floats): [0, 51200) dense coefs [b][o][m]; [51200, 57600) scaled boxes [b][o][4]
#define WS_COEF_   0
#define WS_BOX_    (B_ * NDET_ * NM_)          // 51200
#define GATHER_N_  (B_ * NDET_ * NM_)          // 51200
#define BOXSC_N_   (B_ * NDET_ * 4)            // 6400
#define HEAD_N_    OFF_MASKS_                  // 9616
#define PREP_TOT_  (GATHER_N_ + BOXSC_N_ + HEAD_N_)

typedef float f32x4 __attribute__((ext_vector_type(4)));

// Pre-pass: gather dense coefs, prescale boxes into ws, write small head outputs.
__global__ __launch_bounds__(256) void prep_kernel(
    const float* __restrict__ x0,
    const int*   __restrict__ num_det,
    const float* __restrict__ det_boxes,
    const float* __restrict__ det_scores,
    const int*   __restrict__ det_classes,
    const int*   __restrict__ det_indices,
    float* __restrict__ ws,
    float* __restrict__ out)
{
    int i = blockIdx.x * 256 + threadIdx.x;
    if (i < GATHER_N_) {
        int b = i / (NDET_ * NM_);
        int rem = i - b * (NDET_ * NM_);
        int o = rem >> 5;
        int m = rem & 31;
        int idx = det_indices[b * NDET_ + o];
        ws[WS_COEF_ + i] = x0[((size_t)b * N_ + idx) * XDIM_ + COEF_OFF_ + m];
    } else if (i < GATHER_N_ + BOXSC_N_) {
        int j = i - GATHER_N_;
        ws[WS_BOX_ + j] = det_boxes[j] * 0.25f;
    } else if (i < PREP_TOT_) {
        int j = i - (GATHER_N_ + BOXSC_N_);
        if (j < 16) {
            out[j] = (float)num_det[j];
        } else if (j < OFF_SCORES_) {
            out[j] = det_boxes[j - OFF_BOXES_];
        } else if (j < OFF_CLASSES_) {
            out[j] = det_scores[j - OFF_SCORES_];
        } else {
            out[j] = (float)det_classes[j - OFF_CLASSES_];
        }
    }
}

// Main: 1 px/thread, 256-thread blocks, grid (100 tiles, 16 batches) = 6400 waves.
// All per-detection data (box, 32 coefs) is wave-uniform -> scalar loads, no LDS.
__global__ __launch_bounds__(256) void mask_kernel(
    const float* __restrict__ proto,
    const float* __restrict__ ws,
    float* __restrict__ out)
{
    const int b    = blockIdx.y;
    const int tile = blockIdx.x;
    const int tid  = threadIdx.x;

    const int p = tile * 256 + tid;
    const float rf = (float)(p % W_);
    const float cf = (float)(p / W_);

    // This pixel's proto column (32 values) in registers, coalesced loads.
    const float* __restrict__ pp = proto + (size_t)b * NM_ * HW_ + p;
    float pr[NM_];
#pragma unroll
    for (int m = 0; m < NM_; ++m) pr[m] = pp[(size_t)m * HW_];

    const f32x4* __restrict__ sbox = (const f32x4*)(ws + WS_BOX_) + b * NDET_;
    const float* __restrict__ coef = ws + WS_COEF_ + b * NDET_ * NM_;

    float* __restrict__ outp = out + OFF_MASKS_ + (size_t)b * NDET_ * HW_ + p;

    for (int o = 0; o < NDET_; ++o) {
        const f32x4 bx = sbox[o];                       // uniform -> s_load_dwordx4
        const bool in = (rf >= bx.x) & (rf < bx.z) & (cf >= bx.y) & (cf < bx.w);
        float v = 0.0f;
        if (__ballot(in) != 0) {
            const float* __restrict__ cfp = coef + o * NM_;  // uniform -> s_load
            float acc = 0.0f;
#pragma unroll
            for (int m = 0; m < NM_; ++m) acc += cfp[m] * pr[m];
            float s = 1.0f / (1.0f + __expf(-acc));
            v = in ? s : 0.0f;
        }
        outp[(size_t)o * HW_] = v;
    }
}

extern "C" void kernel_launch(void* const* d_in, const int* in_sizes, int n_in,
                              void* d_out, int out_size, void* d_ws, size_t ws_size,
                              hipStream_t stream)
{
    const float* x0          = (const float*)d_in[0];
    const float* proto       = (const float*)d_in[1];
    const int*   num_det     = (const int*)  d_in[2];
    const float* det_boxes   = (const float*)d_in[3];
    const float* det_scores  = (const float*)d_in[4];
    const int*   det_classes = (const int*)  d_in[5];
    const int*   det_indices = (const int*)  d_in[6];
    float* out = (float*)d_out;
    float* ws  = (float*)d_ws;

    prep_kernel<<<(PREP_TOT_ + 255) / 256, 256, 0, stream>>>(
        x0, num_det, det_boxes, det_scores, det_classes, det_indices, ws, out);

    dim3 grid(HW_ / 256, B_);
    mask_kernel<<<grid, 256, 0, stream>>>(proto, ws, out);
}